// Round 2
// baseline (253.734 us; speedup 1.0000x reference)
//
#include <hip/hip_runtime.h>
#include <hip/hip_bf16.h>

// Problem constants (from reference)
#define E_TOTAL 300000
#define N_NODES 50000
#define NDIM    128      // node feature dim
#define KDIM    256      // 2*NDIM = GEMM K
#define HDIM    512      // 2*HIDDEN = GEMM N (both MLP branches fused)
#define BN_EPS  1e-5f

#define APAD 264         // A row stride in bf16 units (256+8): 528B = 132 dw === 4 mod 32 banks -> 2-way (free)

typedef __attribute__((ext_vector_type(8))) short bf16x8;
typedef __attribute__((ext_vector_type(4))) float f32x4;

__device__ __forceinline__ unsigned short f2bf(float f) {
  unsigned u = __float_as_uint(f);
  u += 0x7fffu + ((u >> 16) & 1u);   // round-to-nearest-even
  return (unsigned short)(u >> 16);
}

// ---- prep 1: node_feat fp32 -> bf16 table (halves gather bytes, kills f2bf in hot loop) ----
__global__ void prep_nf_kernel(const float* __restrict__ nf, unsigned short* __restrict__ nfb) {
  int i = blockIdx.x * 256 + threadIdx.x;     // each thread: 4 floats. 50000*128/4 = 1.6M threads exactly
  float4 v = ((const float4*)nf)[i];
  ushort4 o;
  o.x = f2bf(v.x); o.y = f2bf(v.y); o.z = f2bf(v.z); o.w = f2bf(v.w);
  ((ushort4*)nfb)[i] = o;
}

// ---- prep 2: W1 (BN-folded, roll-fused) -> MFMA B-fragment order ----
// Wswz layout: frag (ct,kt) at ((ct*8+kt)*64 + lane)*8 bf16, lane holds
// col = ct*16 + (lane&15), k = kt*32 + (lane>>4)*8 + j  (j=0..7)
// col<256: branch 1. col>=256: branch 2 (roll 16): W1[(k+16)&255].
__global__ void prep_w_kernel(const float* __restrict__ W1,
                              const float* __restrict__ gamma, const float* __restrict__ var,
                              unsigned short* __restrict__ Wswz) {
  int ct   = blockIdx.x;          // 0..31
  int kt   = threadIdx.x >> 6;    // 0..7
  int lane = threadIdx.x & 63;
  int col  = ct * 16 + (lane & 15);
  int quad = lane >> 4;
  int jj   = col & 255;
  int shift = (col >= 256) ? 16 : 0;
  float s = gamma[jj] * rsqrtf(var[jj] + BN_EPS);
  unsigned short o[8];
  #pragma unroll
  for (int j = 0; j < 8; j++) {
    int k  = kt * 32 + quad * 8 + j;
    int ks = (k + shift) & 255;
    o[j] = f2bf(W1[ks * 256 + jj] * s);
  }
  *(uint4*)(Wswz + ((size_t)(ct * 8 + kt) * 64 + lane) * 8) = *(const uint4*)o;
}

// ---- prep 3: folded bias + w2 ----
__global__ void prep_cw_kernel(const float* __restrict__ b1, const float* __restrict__ gamma,
                               const float* __restrict__ beta, const float* __restrict__ mean,
                               const float* __restrict__ var, const float* __restrict__ W2,
                               float* __restrict__ cbias, float* __restrict__ w2c) {
  int j = threadIdx.x;            // 0..511
  int jj = j & 255;
  float s = gamma[jj] * rsqrtf(var[jj] + BN_EPS);
  cbias[j] = b1[jj] * s + beta[jj] - mean[jj] * s;
  w2c[j]  = W2[jj];
}

// ---- main: 128 edges/block, 512 threads = 8 waves (2 M-halves x 4 col-strips).
// B comes straight from L2 in fragment order (no LDS, no K-loop barriers).
__global__ __launch_bounds__(512, 2) void edge_mlp_kernel(
    const unsigned short* __restrict__ nfb, const int* __restrict__ eidx,
    const unsigned short* __restrict__ Wswz, const float* __restrict__ cbias,
    const float* __restrict__ w2c, const float* __restrict__ b2,
    float* __restrict__ out) {
  __shared__ unsigned short Al[128 * APAD];   // 66 KB: 128 edges x 256 k (bf16)
  __shared__ float partial[4][128];

  const int tid    = threadIdx.x;
  const int wave   = tid >> 6;
  const int lane   = tid & 63;
  const int l16    = lane & 15;
  const int quad   = lane >> 4;
  const int mhalf  = wave >> 2;   // 0..1: rows [mhalf*64, +64)
  const int cstrip = wave & 3;    // 0..3: cols [cstrip*128, +128)
  const int e0     = blockIdx.x * 128;

  // ---- Stage A: gather bf16 endpoint features. 4096 16B chunks, 8/thread,
  // consecutive threads take consecutive chunks (conflict-free LDS writes, coalesced-per-node reads).
  #pragma unroll
  for (int i = 0; i < 8; i++) {
    int g     = i * 512 + tid;
    int el    = g >> 5;           // local edge 0..127
    int half  = (g >> 4) & 1;     // 0: row-node feats (k 0..127), 1: col-node
    int chunk = g & 15;           // 16B chunk within the 256B half
    int e = e0 + el; if (e >= E_TOTAL) e = E_TOTAL - 1;
    int node = half ? eidx[E_TOTAL + e] : eidx[e];
    const uint4* src = (const uint4*)(nfb + (size_t)node * NDIM + chunk * 8);
    *(uint4*)(Al + el * APAD + half * 128 + chunk * 8) = *src;
  }

  // Per-lane epilogue constants for my 8 column-tiles
  float cj[8], w2j[8];
  #pragma unroll
  for (int nt = 0; nt < 8; nt++) {
    int j = cstrip * 128 + nt * 16 + l16;
    cj[nt]  = cbias[j];
    w2j[nt] = w2c[j];
  }

  f32x4 acc[4][8];
  #pragma unroll
  for (int mt = 0; mt < 4; mt++)
    #pragma unroll
    for (int nt = 0; nt < 8; nt++)
      acc[mt][nt] = (f32x4){0.f, 0.f, 0.f, 0.f};

  __syncthreads();   // A staged — the ONLY barrier before the epilogue

  const bf16x8* Wf = (const bf16x8*)Wswz;

  // ---- K loop: no barriers, B direct from L2 in fragment order ----
  #pragma unroll
  for (int kt = 0; kt < 8; kt++) {
    bf16x8 af[4];
    #pragma unroll
    for (int mt = 0; mt < 4; mt++)
      af[mt] = *(const bf16x8*)(Al + (mhalf * 64 + mt * 16 + l16) * APAD + kt * 32 + quad * 8);

    #pragma unroll
    for (int nt = 0; nt < 8; nt++) {
      int ct = cstrip * 8 + nt;
      bf16x8 bfr = Wf[(ct * 8 + kt) * 64 + lane];   // 1KB coalesced wave load, L1/L2-hit
      #pragma unroll
      for (int mt = 0; mt < 4; mt++)
        acc[mt][nt] = __builtin_amdgcn_mfma_f32_16x16x32_bf16(af[mt], bfr, acc[mt][nt], 0, 0, 0);
    }
  }

  // ---- Epilogue: relu(h+c)*w2, reduce over this wave's 128 cols ----
  // C/D layout: col = lane&15, row = quad*4 + r
  #pragma unroll
  for (int mt = 0; mt < 4; mt++) {
    #pragma unroll
    for (int r = 0; r < 4; r++) {
      float v = 0.f;
      #pragma unroll
      for (int nt = 0; nt < 8; nt++) {
        float h = acc[mt][nt][r] + cj[nt];
        v += fmaxf(h, 0.f) * w2j[nt];
      }
      v += __shfl_xor(v, 1);
      v += __shfl_xor(v, 2);
      v += __shfl_xor(v, 4);
      v += __shfl_xor(v, 8);
      if (l16 == 0) partial[cstrip][mhalf * 64 + mt * 16 + quad * 4 + r] = v;
    }
  }
  __syncthreads();

  if (tid < 128) {
    int e = e0 + tid;
    if (e < E_TOTAL) {
      float s = partial[0][tid] + partial[1][tid] + partial[2][tid] + partial[3][tid];
      float logit = 0.5f * s + b2[0];
      out[e] = 1.0f / (1.0f + __expf(-logit));
    }
  }
}

extern "C" void kernel_launch(void* const* d_in, const int* in_sizes, int n_in,
                              void* d_out, int out_size, void* d_ws, size_t ws_size,
                              hipStream_t stream) {
  const float* node_feat = (const float*)d_in[0];
  const int*   eidx      = (const int*)d_in[1];
  const float* W1        = (const float*)d_in[2];
  const float* b1        = (const float*)d_in[3];
  const float* gamma     = (const float*)d_in[4];
  const float* beta      = (const float*)d_in[5];
  const float* mean      = (const float*)d_in[6];
  const float* var       = (const float*)d_in[7];
  const float* W2        = (const float*)d_in[8];
  const float* b2        = (const float*)d_in[9];
  float* out = (float*)d_out;

  // Workspace: Wswz bf16[512*256] (256KB) | cbias f32[512] | w2c f32[512] | nfb bf16[50000*128] (12.8MB)
  unsigned short* Wswz = (unsigned short*)d_ws;
  float* cbias = (float*)((char*)d_ws + (size_t)HDIM * KDIM * 2);
  float* w2c   = cbias + HDIM;
  unsigned short* nfb = (unsigned short*)(w2c + HDIM);

  prep_nf_kernel<<<(N_NODES * NDIM / 4 + 255) / 256, 256, 0, stream>>>(node_feat, nfb);
  prep_w_kernel<<<32, 512, 0, stream>>>(W1, gamma, var, Wswz);
  prep_cw_kernel<<<1, 512, 0, stream>>>(b1, gamma, beta, mean, var, W2, cbias, w2c);

  int nblocks = (E_TOTAL + 127) / 128;   // 2344
  edge_mlp_kernel<<<nblocks, 512, 0, stream>>>(nfb, eidx, Wswz, cbias, w2c, b2, out);
}

// Round 3
// 212.718 us; speedup vs baseline: 1.1928x; 1.1928x over previous
//
#include <hip/hip_runtime.h>
#include <hip/hip_bf16.h>

// Problem constants (from reference)
#define E_TOTAL 300000
#define N_NODES 50000
#define NDIM    128      // node feature dim
#define KDIM    256      // 2*NDIM = GEMM K
#define HDIM    512      // 2*HIDDEN = GEMM N (both MLP branches fused)
#define BN_EPS  1e-5f
#define NTILES  ((E_TOTAL + 63) / 64)   // 4688 tiles of 64 edges
#define NBLK    256                      // persistent blocks, 1/CU

typedef __attribute__((ext_vector_type(8))) short bf16x8;
typedef __attribute__((ext_vector_type(4))) float f32x4;
typedef const __attribute__((address_space(1))) unsigned int* gas1_t;
typedef __attribute__((address_space(3))) unsigned int* las3_t;

__device__ __forceinline__ unsigned short f2bf(float f) {
  unsigned u = __float_as_uint(f);
  u += 0x7fffu + ((u >> 16) & 1u);   // round-to-nearest-even
  return (unsigned short)(u >> 16);
}

// ---- prep 1: node_feat fp32 -> bf16 table (enables 16B DMA gather, no in-loop cvt) ----
__global__ void prep_nf_kernel(const float* __restrict__ nf, unsigned short* __restrict__ nfb) {
  int i = blockIdx.x * 256 + threadIdx.x;     // 50000*128/4 = 1.6M float4s exactly
  float4 v = ((const float4*)nf)[i];
  ushort4 o;
  o.x = f2bf(v.x); o.y = f2bf(v.y); o.z = f2bf(v.z); o.w = f2bf(v.w);
  ((ushort4*)nfb)[i] = o;
}

// ---- prep 2: W1 (BN-folded, roll-fused) -> MFMA B-fragment order ----
// frag (ct,kt) at ((ct*8+kt)*64 + lane)*8 bf16; lane holds col=ct*16+(lane&15),
// k = kt*32 + (lane>>4)*8 + j. col>=256: roll branch uses W1[(k+16)&255].
__global__ void prep_w_kernel(const float* __restrict__ W1,
                              const float* __restrict__ gamma, const float* __restrict__ var,
                              unsigned short* __restrict__ Wswz) {
  int ct   = blockIdx.x;          // 0..31
  int kt   = threadIdx.x >> 6;    // 0..7
  int lane = threadIdx.x & 63;
  int col  = ct * 16 + (lane & 15);
  int quad = lane >> 4;
  int jj   = col & 255;
  int shift = (col >= 256) ? 16 : 0;
  float s = gamma[jj] * rsqrtf(var[jj] + BN_EPS);
  unsigned short o[8];
  #pragma unroll
  for (int j = 0; j < 8; j++) {
    int k  = kt * 32 + quad * 8 + j;
    int ks = (k + shift) & 255;
    o[j] = f2bf(W1[ks * 256 + jj] * s);
  }
  *(uint4*)(Wswz + ((size_t)(ct * 8 + kt) * 64 + lane) * 8) = *(const uint4*)o;
}

// ---- prep 3: folded bias + w2 ----
__global__ void prep_cw_kernel(const float* __restrict__ b1, const float* __restrict__ gamma,
                               const float* __restrict__ beta, const float* __restrict__ mean,
                               const float* __restrict__ var, const float* __restrict__ W2,
                               float* __restrict__ cbias, float* __restrict__ w2c) {
  int j = threadIdx.x;            // 0..511
  int jj = j & 255;
  float s = gamma[jj] * rsqrtf(var[jj] + BN_EPS);
  cbias[j] = b1[jj] * s + beta[jj] - mean[jj] * s;
  w2c[j]  = W2[jj];
}

// ---- main: persistent, 512 threads = 8 waves. Wave w owns cols [w*64, w*64+64)
// with B entirely in registers (bq[4][8] = 128 VGPR, loaded once).
// A staged per 64-edge tile via global_load_lds DMA into MFMA-fragment order,
// double-buffered. K-loop: ds_read_b128 + MFMA only.
__global__ __launch_bounds__(512, 2) void edge_mlp_kernel(
    const unsigned short* __restrict__ nfb, const int* __restrict__ eidx,
    const unsigned short* __restrict__ Wswz, const float* __restrict__ cbias,
    const float* __restrict__ w2c, const float* __restrict__ b2,
    float* __restrict__ out) {
  __shared__ unsigned short Ab[2][32 * 512];   // 2 x 32KB: 32 frags x 64 lanes x 16B
  __shared__ float partial[2][8][64];

  const int tid  = threadIdx.x;
  const int w    = tid >> 6;
  const int lane = tid & 63;
  const int l16  = lane & 15;
  const int quad = lane >> 4;

  // ---- B into registers (once): wave w -> ct = w*4 .. w*4+3 ----
  const bf16x8* Wf = (const bf16x8*)Wswz;
  bf16x8 bq[4][8];
  #pragma unroll
  for (int n = 0; n < 4; n++)
    #pragma unroll
    for (int kt = 0; kt < 8; kt++)
      bq[n][kt] = Wf[((w * 4 + n) * 8 + kt) * 64 + lane];

  float cj[4], w2j[4];
  #pragma unroll
  for (int n = 0; n < 4; n++) {
    int j = w * 64 + n * 16 + l16;
    cj[n]  = cbias[j];
    w2j[n] = w2c[j];
  }
  const float b2v = b2[0];

  // staging role: wave w stages frags (mt = w&3, kt = (w>>2)*4 + i, i=0..3)
  const int smt   = w & 3;
  const int shalf = w >> 2;          // 0: row-node half (k<128), 1: col-node half
  const int skt0  = shalf * 4;
  const int sfeat = quad * 8;        // feature offset within the 128-dim half

  int t = blockIdx.x;

  // ---- stage first tile into Ab[0] ----
  {
    int e = t * 64 + smt * 16 + l16;
    if (e >= E_TOTAL) e = E_TOTAL - 1;
    int node = eidx[shalf * E_TOTAL + e];
    const unsigned short* gbase = nfb + (size_t)node * NDIM + sfeat;
    #pragma unroll
    for (int i = 0; i < 4; i++)
      __builtin_amdgcn_global_load_lds((gas1_t)(gbase + i * 32),
                                       (las3_t)(&Ab[0][(smt * 8 + skt0 + i) * 512]),
                                       16, 0, 0);
  }
  __syncthreads();

  int p = 0;
  for (; t < NTILES; t += NBLK) {
    // ---- async-stage next tile into the other buffer ----
    int tn = t + NBLK;
    if (tn < NTILES) {
      int e = tn * 64 + smt * 16 + l16;
      if (e >= E_TOTAL) e = E_TOTAL - 1;
      int node = eidx[shalf * E_TOTAL + e];
      const unsigned short* gbase = nfb + (size_t)node * NDIM + sfeat;
      #pragma unroll
      for (int i = 0; i < 4; i++)
        __builtin_amdgcn_global_load_lds((gas1_t)(gbase + i * 32),
                                         (las3_t)(&Ab[p ^ 1][(smt * 8 + skt0 + i) * 512]),
                                         16, 0, 0);
    }

    // ---- compute: 8 kt x (4 ds_read_b128 + 16 MFMA) ----
    f32x4 acc[4][4];
    #pragma unroll
    for (int mt = 0; mt < 4; mt++)
      #pragma unroll
      for (int n = 0; n < 4; n++)
        acc[mt][n] = (f32x4){0.f, 0.f, 0.f, 0.f};

    #pragma unroll
    for (int kt = 0; kt < 8; kt++) {
      bf16x8 af[4];
      #pragma unroll
      for (int mt = 0; mt < 4; mt++)
        af[mt] = *(const bf16x8*)(&Ab[p][(mt * 8 + kt) * 512 + lane * 8]);
      #pragma unroll
      for (int n = 0; n < 4; n++)
        #pragma unroll
        for (int mt = 0; mt < 4; mt++)
          acc[mt][n] = __builtin_amdgcn_mfma_f32_16x16x32_bf16(af[mt], bq[n][kt], acc[mt][n], 0, 0, 0);
    }

    // ---- epilogue: relu(h+c)*w2, reduce over this wave's 64 cols ----
    // C/D layout: col = lane&15, row = quad*4 + r
    #pragma unroll
    for (int mt = 0; mt < 4; mt++) {
      #pragma unroll
      for (int r = 0; r < 4; r++) {
        float v = 0.f;
        #pragma unroll
        for (int n = 0; n < 4; n++) {
          float h = acc[mt][n][r] + cj[n];
          v += fmaxf(h, 0.f) * w2j[n];
        }
        v += __shfl_xor(v, 1);
        v += __shfl_xor(v, 2);
        v += __shfl_xor(v, 4);
        v += __shfl_xor(v, 8);
        if (l16 == 0) partial[p][w][mt * 16 + quad * 4 + r] = v;
      }
    }

    __syncthreads();   // drains next-tile DMA (landed long ago) + publishes partial

    // ---- final combine + sigmoid (wave 0 only; overlaps next tile for waves 1-7) ----
    if (tid < 64) {
      int e = t * 64 + tid;
      if (e < E_TOTAL) {
        float s = 0.f;
        #pragma unroll
        for (int ww = 0; ww < 8; ww++) s += partial[p][ww][tid];
        float logit = 0.5f * s + b2v;
        out[e] = 1.0f / (1.0f + __expf(-logit));
      }
    }
    p ^= 1;
  }
}

extern "C" void kernel_launch(void* const* d_in, const int* in_sizes, int n_in,
                              void* d_out, int out_size, void* d_ws, size_t ws_size,
                              hipStream_t stream) {
  const float* node_feat = (const float*)d_in[0];
  const int*   eidx      = (const int*)d_in[1];
  const float* W1        = (const float*)d_in[2];
  const float* b1        = (const float*)d_in[3];
  const float* gamma     = (const float*)d_in[4];
  const float* beta      = (const float*)d_in[5];
  const float* mean      = (const float*)d_in[6];
  const float* var       = (const float*)d_in[7];
  const float* W2        = (const float*)d_in[8];
  const float* b2        = (const float*)d_in[9];
  float* out = (float*)d_out;

  // Workspace: Wswz bf16[512*256] (256KB) | cbias f32[512] | w2c f32[512] | nfb bf16[50000*128] (12.8MB)
  unsigned short* Wswz = (unsigned short*)d_ws;
  float* cbias = (float*)((char*)d_ws + (size_t)HDIM * KDIM * 2);
  float* w2c   = cbias + HDIM;
  unsigned short* nfb = (unsigned short*)(w2c + HDIM);

  prep_nf_kernel<<<(N_NODES * NDIM / 4 + 255) / 256, 256, 0, stream>>>(node_feat, nfb);
  prep_w_kernel<<<32, 512, 0, stream>>>(W1, gamma, var, Wswz);
  prep_cw_kernel<<<1, 512, 0, stream>>>(b1, gamma, beta, mean, var, W2, cbias, w2c);

  edge_mlp_kernel<<<NBLK, 512, 0, stream>>>(nfb, eidx, Wswz, cbias, w2c, b2, out);
}